// Round 1
// baseline (400.356 us; speedup 1.0000x reference)
//
#include <hip/hip_runtime.h>
#include <stdint.h>

// Z9QATAttention: out = softmax_causal((x@Wqkv).q @ (x@Wqkv).k^T * D^-0.5) @ v @ Wout
// charge_bias = fmod(sum(charge_w),9)*1e-3 is added uniformly to all logits BEFORE the
// masked positions are REPLACED by -1e9 -> softmax is shift-invariant -> bias is a no-op.
// mask is tril(ones) -> implemented as causal predicate (kv <= q).

typedef __attribute__((ext_vector_type(4))) float f32x4;
typedef __attribute__((ext_vector_type(8))) __bf16 bf16x8;
typedef __attribute__((ext_vector_type(8))) unsigned short ushort8;
typedef __attribute__((ext_vector_type(4))) unsigned short ushort4v;

#define DEV __device__ __forceinline__

DEV unsigned short f32_to_bf16(float f) {
    union { float f; unsigned int u; } cv; cv.f = f;
    unsigned int u = cv.u;
    return (unsigned short)((u + 0x7FFFu + ((u >> 16) & 1u)) >> 16);
}

DEV bf16x8 load_bf16x8(const unsigned short* p) {
    ushort8 v = *(const ushort8*)p;
    return __builtin_bit_cast(bf16x8, v);
}

// ---------------- fp32 -> bf16 conversion (vectorized) ----------------
__global__ void cvt_kernel(const float* __restrict__ in, unsigned short* __restrict__ out, int n) {
    int i = (blockIdx.x * blockDim.x + threadIdx.x) * 4;
    if (i >= n) return;
    f32x4 v = *(const f32x4*)(in + i);
    ushort4v o;
    o[0] = f32_to_bf16(v[0]);
    o[1] = f32_to_bf16(v[1]);
    o[2] = f32_to_bf16(v[2]);
    o[3] = f32_to_bf16(v[3]);
    *(ushort4v*)(out + i) = o;
}

// ---------------- bf16 MFMA GEMM: C[M,N] = A[M,K] @ B[K,N] ----------------
// A row-major (lda == K), B row-major (ldb), 128x128 tile, 4 waves 2x2, BK=32.
template<bool OUT_BF16>
__global__ __launch_bounds__(256) void gemm_kernel(
    const unsigned short* __restrict__ A,
    const unsigned short* __restrict__ B,
    void* __restrict__ C,
    int K, int ldb, int ldc)
{
    __shared__ __align__(16) unsigned short As[128][40];   // +8 pad: 2-way conflicts only
    __shared__ __align__(16) unsigned short Bts[128][40];  // B transposed: [n][k]

    const int tid = threadIdx.x;
    const int lane = tid & 63;
    const int w = tid >> 6;
    const int wr = w >> 1, wc = w & 1;
    const int g = lane >> 4, ci = lane & 15;
    const int bx = blockIdx.x, by = blockIdx.y;

    f32x4 acc[4][4];
#pragma unroll
    for (int i = 0; i < 4; ++i)
#pragma unroll
        for (int j = 0; j < 4; ++j) acc[i][j] = f32x4{0.f, 0.f, 0.f, 0.f};

    for (int k0 = 0; k0 < K; k0 += 32) {
        __syncthreads();
        // stage A tile: 128 rows x 32 cols
#pragma unroll
        for (int hh = 0; hh < 2; ++hh) {
            int sid = tid + hh * 256;            // 512 segments of 8 elems
            int row = sid >> 2, s = sid & 3;
            ushort8 v = *(const ushort8*)(A + (size_t)(by * 128 + row) * K + k0 + s * 8);
            *(ushort8*)&As[row][s * 8] = v;
        }
        // stage B tile transposed: 32 k-rows x 128 n-cols -> Bts[n][k]
#pragma unroll
        for (int hh = 0; hh < 2; ++hh) {
            int sid = tid + hh * 256;
            int kk = sid >> 4, s = sid & 15;
            ushort8 v = *(const ushort8*)(B + (size_t)(k0 + kk) * ldb + bx * 128 + s * 8);
#pragma unroll
            for (int j = 0; j < 8; ++j) Bts[s * 8 + j][kk] = v[j];
        }
        __syncthreads();

        bf16x8 af[4], bfr[4];
#pragma unroll
        for (int mf = 0; mf < 4; ++mf) af[mf] = load_bf16x8(&As[wr * 64 + mf * 16 + ci][g * 8]);
#pragma unroll
        for (int nf = 0; nf < 4; ++nf) bfr[nf] = load_bf16x8(&Bts[wc * 64 + nf * 16 + ci][g * 8]);
#pragma unroll
        for (int mf = 0; mf < 4; ++mf)
#pragma unroll
            for (int nf = 0; nf < 4; ++nf)
                acc[mf][nf] = __builtin_amdgcn_mfma_f32_16x16x32_bf16(af[mf], bfr[nf], acc[mf][nf], 0, 0, 0);
    }

#pragma unroll
    for (int mf = 0; mf < 4; ++mf)
#pragma unroll
        for (int nf = 0; nf < 4; ++nf)
#pragma unroll
            for (int r = 0; r < 4; ++r) {
                int row = by * 128 + wr * 64 + mf * 16 + g * 4 + r;  // C/D: row=(lane>>4)*4+reg
                int col = bx * 128 + wc * 64 + nf * 16 + ci;         //      col=lane&15
                if (OUT_BF16)
                    ((unsigned short*)C)[(size_t)row * ldc + col] = f32_to_bf16(acc[mf][nf][r]);
                else
                    ((float*)C)[(size_t)row * ldc + col] = acc[mf][nf][r];
            }
}

// ---------------- causal flash attention, bf16 MFMA ----------------
// qkv: (B*T, 3*C) bf16, per (b,h): Q rows at +0, K at +C, V at +2C, head offset h*64.
// Block: 64 q-rows (4 waves x 16), iterate kv tiles of 32.
__global__ __launch_bounds__(256) void attn_kernel(
    const unsigned short* __restrict__ qkv,
    unsigned short* __restrict__ out)
{
    constexpr int T = 2048, HD3 = 3072, C = 1024;
    __shared__ __align__(16) unsigned short Ks[32][72];      // K tile row-major [kv][d]
    __shared__ __align__(16) unsigned short Vts[64][40];     // V tile transposed [d][kv]
    __shared__ __align__(16) unsigned short Ps[4][16][40];   // per-wave P [q][kv]

    const int tid = threadIdx.x;
    const int lane = tid & 63;
    const int w = tid >> 6;
    const int g = lane >> 4, ci = lane & 15;

    const int qb = blockIdx.x & 31;
    const int h = (blockIdx.x >> 5) & 15;
    const int b = blockIdx.x >> 9;
    const int q0 = qb * 64;
    const size_t base = (size_t)b * T * HD3;

    // Q fragments (row = lane&15, k-dim = d split in two 32-chunks)
    bf16x8 aq[2];
    {
        int qrow = q0 + w * 16 + ci;
        const unsigned short* qp = qkv + base + (size_t)qrow * HD3 + h * 64;
        aq[0] = load_bf16x8(qp + g * 8);
        aq[1] = load_bf16x8(qp + 32 + g * 8);
    }

    float m_r[4], l_r[4];
    f32x4 acc[4];
#pragma unroll
    for (int r = 0; r < 4; ++r) { m_r[r] = -1e30f; l_r[r] = 0.f; }
#pragma unroll
    for (int d = 0; d < 4; ++d) acc[d] = f32x4{0.f, 0.f, 0.f, 0.f};

    const int ntiles = 2 * qb + 2;
    for (int t = 0; t < ntiles; ++t) {
        const int kv0 = t * 32;
        __syncthreads();
        {   // stage K (row-major) and V (transposed): 32 rows x 64 d, 8 elems/thread each
            int row = tid >> 3, s = tid & 7;
            const unsigned short* kp = qkv + base + (size_t)(kv0 + row) * HD3 + C + h * 64 + s * 8;
            ushort8 kvz = *(const ushort8*)kp;
            *(ushort8*)&Ks[row][s * 8] = kvz;
            const unsigned short* vp = qkv + base + (size_t)(kv0 + row) * HD3 + 2 * C + h * 64 + s * 8;
            ushort8 vv = *(const ushort8*)vp;
#pragma unroll
            for (int j = 0; j < 8; ++j) Vts[s * 8 + j][row] = vv[j];
        }
        __syncthreads();

        // S = Q @ K^T for two 16-col blocks of this 32-wide kv tile
        f32x4 s0 = {0.f, 0.f, 0.f, 0.f}, s1 = {0.f, 0.f, 0.f, 0.f};
        {
            bf16x8 bk00 = load_bf16x8(&Ks[ci][g * 8]);
            bf16x8 bk01 = load_bf16x8(&Ks[ci][32 + g * 8]);
            s0 = __builtin_amdgcn_mfma_f32_16x16x32_bf16(aq[0], bk00, s0, 0, 0, 0);
            s0 = __builtin_amdgcn_mfma_f32_16x16x32_bf16(aq[1], bk01, s0, 0, 0, 0);
            bf16x8 bk10 = load_bf16x8(&Ks[16 + ci][g * 8]);
            bf16x8 bk11 = load_bf16x8(&Ks[16 + ci][32 + g * 8]);
            s1 = __builtin_amdgcn_mfma_f32_16x16x32_bf16(aq[0], bk10, s1, 0, 0, 0);
            s1 = __builtin_amdgcn_mfma_f32_16x16x32_bf16(aq[1], bk11, s1, 0, 0, 0);
        }

        const float scale = 0.125f;  // D^-0.5
#pragma unroll
        for (int r = 0; r < 4; ++r) {
            int qrow = q0 + w * 16 + g * 4 + r;
            float v0 = s0[r] * scale;
            float v1 = s1[r] * scale;
            if (kv0 + ci > qrow) v0 = -1e30f;        // causal mask
            if (kv0 + 16 + ci > qrow) v1 = -1e30f;
            float tm = fmaxf(v0, v1);
            tm = fmaxf(tm, __shfl_xor(tm, 1));
            tm = fmaxf(tm, __shfl_xor(tm, 2));
            tm = fmaxf(tm, __shfl_xor(tm, 4));
            tm = fmaxf(tm, __shfl_xor(tm, 8));
            float mnew = fmaxf(m_r[r], tm);
            float alpha = __expf(m_r[r] - mnew);
            float p0 = __expf(v0 - mnew);
            float p1 = __expf(v1 - mnew);
            float rs = p0 + p1;
            rs += __shfl_xor(rs, 1);
            rs += __shfl_xor(rs, 2);
            rs += __shfl_xor(rs, 4);
            rs += __shfl_xor(rs, 8);
            l_r[r] = l_r[r] * alpha + rs;
            m_r[r] = mnew;
            Ps[w][g * 4 + r][ci] = f32_to_bf16(p0);
            Ps[w][g * 4 + r][16 + ci] = f32_to_bf16(p1);
#pragma unroll
            for (int d = 0; d < 4; ++d) acc[d][r] *= alpha;
        }

        // O += P @ V   (A = P from LDS, B = V^T tile)
        bf16x8 ap = load_bf16x8(&Ps[w][ci][g * 8]);
#pragma unroll
        for (int d = 0; d < 4; ++d) {
            bf16x8 bv = load_bf16x8(&Vts[d * 16 + ci][g * 8]);
            acc[d] = __builtin_amdgcn_mfma_f32_16x16x32_bf16(ap, bv, acc[d], 0, 0, 0);
        }
    }

    // epilogue: O / l, write bf16 attn output in (B,T,H,D)=(B,T,C) layout
#pragma unroll
    for (int d = 0; d < 4; ++d)
#pragma unroll
        for (int r = 0; r < 4; ++r) {
            int qrow = q0 + w * 16 + g * 4 + r;
            float v = acc[d][r] / l_r[r];
            out[(size_t)b * T * C + (size_t)qrow * C + h * 64 + d * 16 + ci] = f32_to_bf16(v);
        }
}

extern "C" void kernel_launch(void* const* d_in, const int* in_sizes, int n_in,
                              void* d_out, int out_size, void* d_ws, size_t ws_size,
                              hipStream_t stream) {
    const float* x     = (const float*)d_in[0];
    // d_in[1] = mask (tril by construction -> causal predicate), unused
    const float* w_qkv = (const float*)d_in[2];
    const float* w_out = (const float*)d_in[3];
    // d_in[4] = charge_w: provably no-op (uniform pre-mask logit shift), unused
    float* out = (float*)d_out;

    // workspace layout (bf16 elements): 48 MB total
    unsigned short* xb    = (unsigned short*)d_ws;
    unsigned short* wqkvb = xb + 4194304;        // 4096*1024
    unsigned short* woutb = wqkvb + 3145728;     // 1024*3072
    unsigned short* qkv   = woutb + 1048576;     // 1024*1024
    unsigned short* attn  = qkv + 12582912;      // 4096*3072

    cvt_kernel<<<4096, 256, 0, stream>>>(x, xb, 4194304);
    cvt_kernel<<<3072, 256, 0, stream>>>(w_qkv, wqkvb, 3145728);
    cvt_kernel<<<1024, 256, 0, stream>>>(w_out, woutb, 1048576);

    // qkv = xb @ w_qkv  (M=4096, N=3072, K=1024), bf16 out
    gemm_kernel<true><<<dim3(24, 32), 256, 0, stream>>>(xb, wqkvb, (void*)qkv, 1024, 3072, 3072);

    // causal attention per (b, h, 64-row q-tile)
    attn_kernel<<<1024, 256, 0, stream>>>(qkv, attn);

    // out = attn @ w_out (M=4096, N=1024, K=1024), fp32 out
    gemm_kernel<false><<<dim3(8, 32), 256, 0, stream>>>(attn, woutb, (void*)out, 1024, 1024, 1024);
}

// Round 3
// 169.911 us; speedup vs baseline: 2.3563x; 2.3563x over previous
//
#include <hip/hip_runtime.h>
#include <stdint.h>

// Z9QATAttention: out = softmax_causal((x@Wqkv).q @ (x@Wqkv).k^T * D^-0.5) @ v @ Wout
// charge_bias: uniform pre-mask logit shift -> softmax-invariant -> no-op.
// mask == tril -> causal predicate. Softmax scale*log2e folded into q columns in GEMM1.

typedef __attribute__((ext_vector_type(4))) float f32x4;
typedef __attribute__((ext_vector_type(16))) float f32x16;
typedef __attribute__((ext_vector_type(8))) __bf16 bf16x8;
typedef __attribute__((ext_vector_type(8))) unsigned short ushort8;
typedef __attribute__((ext_vector_type(4))) unsigned short ushort4v;
typedef __attribute__((ext_vector_type(4))) unsigned int uint4v;

#define DEV __device__ __forceinline__

DEV unsigned short f32_to_bf16(float f) {
    union { float f; unsigned int u; } cv; cv.f = f;
    unsigned int u = cv.u;
    return (unsigned short)((u + 0x7FFFu + ((u >> 16) & 1u)) >> 16);
}

DEV bf16x8 load_bf16x8(const unsigned short* p) {
    ushort8 v = *(const ushort8*)p;
    return __builtin_bit_cast(bf16x8, v);
}

DEV unsigned cvt_pk_bf16(float lo, float hi) {
    unsigned r;
    asm("v_cvt_pk_bf16_f32 %0, %1, %2" : "=v"(r) : "v"(lo), "v"(hi));
    return r;
}

DEV void gload_lds16(const void* g, void* l) {
    __builtin_amdgcn_global_load_lds(
        (const __attribute__((address_space(1))) unsigned int*)g,
        (__attribute__((address_space(3))) unsigned int*)l, 16, 0, 0);
}

DEV f32x16 vzero16() {
    f32x16 v;
#pragma unroll
    for (int i = 0; i < 16; ++i) v[i] = 0.f;
    return v;
}

// ---------------- fp32 -> bf16 conversion ----------------
__global__ void cvt_kernel(const float* __restrict__ in, unsigned short* __restrict__ out, int n) {
    int i = (blockIdx.x * blockDim.x + threadIdx.x) * 4;
    if (i >= n) return;
    f32x4 v = *(const f32x4*)(in + i);
    ushort4v o;
    o[0] = f32_to_bf16(v[0]); o[1] = f32_to_bf16(v[1]);
    o[2] = f32_to_bf16(v[2]); o[3] = f32_to_bf16(v[3]);
    *(ushort4v*)(out + i) = o;
}

// ---------------- fp32 -> bf16 transpose: out[c][r] = bf16(in[r][c]) ----------------
__global__ __launch_bounds__(256) void tcvt_kernel(const float* __restrict__ in,
                                                   unsigned short* __restrict__ out,
                                                   int R, int Cn) {
    __shared__ float tl[32][33];
    const int tx = threadIdx.x & 31, ty = threadIdx.x >> 5;
    const int c0 = blockIdx.x * 32, r0 = blockIdx.y * 32;
#pragma unroll
    for (int rr = 0; rr < 4; ++rr) {
        int r = ty + rr * 8;
        tl[r][tx] = in[(size_t)(r0 + r) * Cn + c0 + tx];
    }
    __syncthreads();
#pragma unroll
    for (int rr = 0; rr < 4; ++rr) {
        int cc = ty + rr * 8;
        out[(size_t)(c0 + cc) * R + r0 + tx] = f32_to_bf16(tl[tx][cc]);
    }
}

// ---------------- bf16 MFMA GEMM (m97 pattern): C[M,N] = A[M,K] @ Bt[N,K]^T ----------------
template<bool OUT_BF16, bool SCALE_Q>
__global__ __launch_bounds__(256) void gemm_kernel(
    const unsigned short* __restrict__ A,
    const unsigned short* __restrict__ Bt,
    void* __restrict__ C, int K, int ldc)
{
    __shared__ __align__(16) unsigned short As[128 * 32];
    __shared__ __align__(16) unsigned short Bs[128 * 32];

    const int tid = threadIdx.x;
    const int lane = tid & 63;
    const int w = tid >> 6;
    const int wr = w >> 1, wc = w & 1;
    const int g = lane >> 4, ci = lane & 15;
    const int bx = blockIdx.x, by = blockIdx.y;

    f32x4 acc[4][4];
#pragma unroll
    for (int i = 0; i < 4; ++i)
#pragma unroll
        for (int j = 0; j < 4; ++j) acc[i][j] = f32x4{0.f, 0.f, 0.f, 0.f};

    for (int k0 = 0; k0 < K; k0 += 32) {
        __syncthreads();
#pragma unroll
        for (int i = 0; i < 2; ++i) {
            int off = i * 4096 + w * 1024 + lane * 16;   // byte offset in LDS tile
            int row = off >> 6;                           // 64B per row (BK=32 bf16)
            int cch = (off >> 4) & 3;
            gload_lds16(A  + (size_t)(by * 128 + row) * K + k0 + cch * 8,
                        (char*)As + i * 4096 + w * 1024);
            gload_lds16(Bt + (size_t)(bx * 128 + row) * K + k0 + cch * 8,
                        (char*)Bs + i * 4096 + w * 1024);
        }
        __syncthreads();

        bf16x8 af[4], bfr[4];
#pragma unroll
        for (int mf = 0; mf < 4; ++mf) af[mf]  = load_bf16x8(&As[(wr * 64 + mf * 16 + ci) * 32 + g * 8]);
#pragma unroll
        for (int nf = 0; nf < 4; ++nf) bfr[nf] = load_bf16x8(&Bs[(wc * 64 + nf * 16 + ci) * 32 + g * 8]);
#pragma unroll
        for (int mf = 0; mf < 4; ++mf)
#pragma unroll
            for (int nf = 0; nf < 4; ++nf)
                acc[mf][nf] = __builtin_amdgcn_mfma_f32_16x16x32_bf16(af[mf], bfr[nf], acc[mf][nf], 0, 0, 0);
    }

#pragma unroll
    for (int mf = 0; mf < 4; ++mf)
#pragma unroll
        for (int nf = 0; nf < 4; ++nf)
#pragma unroll
            for (int r = 0; r < 4; ++r) {
                int row = by * 128 + wr * 64 + mf * 16 + g * 4 + r;
                int col = bx * 128 + wc * 64 + nf * 16 + ci;
                float v = acc[mf][nf][r];
                if (SCALE_Q && col < 1024) v *= 0.1803368801f;  // D^-0.5 * log2(e)
                if (OUT_BF16)
                    ((unsigned short*)C)[(size_t)row * ldc + col] = f32_to_bf16(v);
                else
                    ((float*)C)[(size_t)row * ldc + col] = v;
            }
}

// ---------------- causal flash attention, 32x32x16 MFMA, swapped operands ----------------
// 4 waves x 32 q-rows (QBLK=128), KVBLK=64, double-buffered K (global_load_lds, swizzled
// source) and V^T (reg-staged, XOR-swizzled). S^T = mfma(K, Q^T): lane holds one q-row.
__global__ __launch_bounds__(256) void attn2_kernel(const unsigned short* __restrict__ qkv,
                                                    unsigned short* __restrict__ attn) {
    constexpr int T = 2048, HD3 = 3072, Cc = 1024;
    __shared__ __align__(16) unsigned short Ks[2][4096];  // [64 kv][64 d], col ^= (row&7)*8
    __shared__ __align__(16) unsigned short Vt[2][4096];  // [64 d][64 kv], col ^= ((d^(d>>3))&7)*8

    const int tid = threadIdx.x;
    const int lane = tid & 63;
    const int w = tid >> 6;
    const int l31 = lane & 31;
    const int hi = lane >> 5;

    const int bx = blockIdx.x;
    const int qb = bx & 15;
    const int h = (bx >> 4) & 15;
    const int b = bx >> 8;
    const int q0w = qb * 128 + w * 32;
    const int qrow = q0w + l31;
    const size_t base = (size_t)b * T * HD3;

    bf16x8 qf[4];   // B-operand: lane holds Q[qrow][t*16 + hi*8 + j] (q pre-scaled in GEMM1)
#pragma unroll
    for (int t = 0; t < 4; ++t)
        qf[t] = load_bf16x8(qkv + base + (size_t)qrow * HD3 + h * 64 + t * 16 + hi * 8);

    f32x16 acc0 = vzero16(), acc1 = vzero16();  // O^T: col=q(lane), row d = rr+8G+4hi (+32)
    float m = -3e38f, l = 0.f;
    const int nt = 2 * qb + 2;

    ushort8 vl0, vl1;
#define LOADV(tile) do { int kv0_ = (tile) * 64; \
    int r0_ = tid >> 3, cc0_ = tid & 7; \
    vl0 = *(const ushort8*)(qkv + base + (size_t)(kv0_ + r0_) * HD3 + 2 * Cc + h * 64 + cc0_ * 8); \
    int c1_ = 256 + tid; int r1_ = c1_ >> 3, cc1_ = c1_ & 7; \
    vl1 = *(const ushort8*)(qkv + base + (size_t)(kv0_ + r1_) * HD3 + 2 * Cc + h * 64 + cc1_ * 8); } while (0)

#define DMAK(tile, buf) do { int kv0_ = (tile) * 64; \
    _Pragma("unroll") for (int i_ = 0; i_ < 2; ++i_) { \
        int off_ = i_ * 4096 + w * 1024 + lane * 16; \
        int row_ = off_ >> 7; \
        int csw_ = ((lane & 7) * 8) ^ ((row_ & 7) * 8); \
        gload_lds16(qkv + base + (size_t)(kv0_ + row_) * HD3 + Cc + h * 64 + csw_, \
                    (void*)(((char*)&Ks[buf][0]) + i_ * 4096 + w * 1024)); } } while (0)

#define WRITEV(buf) do { \
    _Pragma("unroll") for (int i_ = 0; i_ < 2; ++i_) { \
        int c_ = i_ * 256 + tid; int row_ = c_ >> 3, cc_ = c_ & 7; \
        ushort8 v_ = i_ ? vl1 : vl0; \
        _Pragma("unroll") for (int j_ = 0; j_ < 8; ++j_) { \
            int d_ = cc_ * 8 + j_; \
            int sw_ = ((d_ ^ (d_ >> 3)) & 7) * 8; \
            Vt[buf][d_ * 64 + (row_ ^ sw_)] = v_[j_]; } } } while (0)

    LOADV(0); DMAK(0, 0); WRITEV(0);
    __syncthreads();

    for (int t = 0; t < nt; ++t) {
        const int kv0 = t * 64;
        const int cur = t & 1;
        const bool act = (kv0 <= q0w + 31);
        const bool pre = (t + 1) < nt;
        if (pre) { LOADV(t + 1); DMAK(t + 1, cur ^ 1); }

        f32x16 s0 = vzero16(), s1 = vzero16();
        bf16x8 pf[4];
        if (act) {
            const bool st1_ok = (kv0 + 32 <= q0w + 31);
#pragma unroll
            for (int tt = 0; tt < 4; ++tt) {  // st = 0
                int row = l31;
                int idx = row * 64 + ((tt * 16 + hi * 8) ^ ((row & 7) * 8));
                s0 = __builtin_amdgcn_mfma_f32_32x32x16_bf16(load_bf16x8(&Ks[cur][idx]), qf[tt], s0, 0, 0, 0);
            }
            if (st1_ok) {
#pragma unroll
                for (int tt = 0; tt < 4; ++tt) {  // st = 1
                    int row = 32 + l31;
                    int idx = row * 64 + ((tt * 16 + hi * 8) ^ ((row & 7) * 8));
                    s1 = __builtin_amdgcn_mfma_f32_32x32x16_bf16(load_bf16x8(&Ks[cur][idx]), qf[tt], s1, 0, 0, 0);
                }
            }
            const bool needmask = (kv0 + 63 > q0w);
            if (needmask) {
#pragma unroll
                for (int G = 0; G < 4; ++G)
#pragma unroll
                    for (int rr = 0; rr < 4; ++rr) {
                        int kvb = kv0 + 8 * G + 4 * hi + rr;  // kv of C-reg (crow formula, HW-verified)
                        s0[G * 4 + rr] = (kvb      <= qrow) ? s0[G * 4 + rr] : -3e38f;
                        s1[G * 4 + rr] = (kvb + 32 <= qrow) ? s1[G * 4 + rr] : -3e38f;
                    }
            }
            float pmax = -3e38f;
#pragma unroll
            for (int i = 0; i < 16; ++i) pmax = fmaxf(pmax, fmaxf(s0[i], s1[i]));
            pmax = fmaxf(pmax, __shfl_xor(pmax, 32));
            float mnew = fmaxf(m, pmax);
            float alpha = exp2f(m - mnew);
            m = mnew;
            float rs = 0.f;
#pragma unroll
            for (int i = 0; i < 16; ++i) {
                s0[i] = exp2f(s0[i] - mnew);
                s1[i] = exp2f(s1[i] - mnew);
                rs += s0[i] + s1[i];
            }
            rs += __shfl_xor(rs, 32);
            l = l * alpha + rs;
#pragma unroll
            for (int i = 0; i < 16; ++i) { acc0[i] *= alpha; acc1[i] *= alpha; }

            // P -> B-fragments, fully in-register (cvt_pk + lane<->lane+32 swap)
            unsigned pk0[4][2], pk1[4][2];
#pragma unroll
            for (int G = 0; G < 4; ++G) {
                pk0[G][0] = cvt_pk_bf16(s0[G * 4 + 0], s0[G * 4 + 1]);
                pk0[G][1] = cvt_pk_bf16(s0[G * 4 + 2], s0[G * 4 + 3]);
                pk1[G][0] = cvt_pk_bf16(s1[G * 4 + 0], s1[G * 4 + 1]);
                pk1[G][1] = cvt_pk_bf16(s1[G * 4 + 2], s1[G * 4 + 3]);
            }
#pragma unroll
            for (int tf = 0; tf < 4; ++tf) {
                const int kb = tf & 1;
                unsigned sA0, sA1, sB0, sB1;
                if (tf < 2) { sA0 = pk0[2 * kb][0]; sA1 = pk0[2 * kb][1]; sB0 = pk0[2 * kb + 1][0]; sB1 = pk0[2 * kb + 1][1]; }
                else        { sA0 = pk1[2 * kb][0]; sA1 = pk1[2 * kb][1]; sB0 = pk1[2 * kb + 1][0]; sB1 = pk1[2 * kb + 1][1]; }
                unsigned sd0 = hi ? sA0 : sB0, sd1 = hi ? sA1 : sB1;
                unsigned rc0 = (unsigned)__shfl_xor((int)sd0, 32);
                unsigned rc1 = (unsigned)__shfl_xor((int)sd1, 32);
                uint4v u;
                u[0] = hi ? rc0 : sA0;  u[1] = hi ? rc1 : sA1;   // k = hi*8 + 0..3
                u[2] = hi ? sB0 : rc0;  u[3] = hi ? sB1 : rc1;   // k = hi*8 + 4..7
                pf[tf] = __builtin_bit_cast(bf16x8, u);
            }
        }

        if (pre) WRITEV(cur ^ 1);   // compiler waits the V global loads here

        if (act) {
#pragma unroll
            for (int tt = 0; tt < 4; ++tt) {
                {
                    int d = l31, sw = ((d ^ (d >> 3)) & 7) * 8;
                    bf16x8 vf = load_bf16x8(&Vt[cur][d * 64 + ((tt * 16 + hi * 8) ^ sw)]);
                    acc0 = __builtin_amdgcn_mfma_f32_32x32x16_bf16(vf, pf[tt], acc0, 0, 0, 0);
                }
                {
                    int d = 32 + l31, sw = ((d ^ (d >> 3)) & 7) * 8;
                    bf16x8 vf = load_bf16x8(&Vt[cur][d * 64 + ((tt * 16 + hi * 8) ^ sw)]);
                    acc1 = __builtin_amdgcn_mfma_f32_32x32x16_bf16(vf, pf[tt], acc1, 0, 0, 0);
                }
            }
        }
        __syncthreads();
    }

    const float invl = 1.0f / l;
    const size_t ob = (size_t)b * T * Cc + (size_t)qrow * Cc + h * 64;
#pragma unroll
    for (int G = 0; G < 4; ++G) {
        ushort4v o0, o1;
#pragma unroll
        for (int rr = 0; rr < 4; ++rr) {
            o0[rr] = f32_to_bf16(acc0[G * 4 + rr] * invl);
            o1[rr] = f32_to_bf16(acc1[G * 4 + rr] * invl);
        }
        int d0 = 8 * G + 4 * hi;
        *(ushort4v*)(attn + ob + d0) = o0;
        *(ushort4v*)(attn + ob + 32 + d0) = o1;
    }
#undef LOADV
#undef DMAK
#undef WRITEV
}

extern "C" void kernel_launch(void* const* d_in, const int* in_sizes, int n_in,
                              void* d_out, int out_size, void* d_ws, size_t ws_size,
                              hipStream_t stream) {
    const float* x     = (const float*)d_in[0];
    // d_in[1] = mask (tril -> causal predicate), unused
    const float* w_qkv = (const float*)d_in[2];
    const float* w_out = (const float*)d_in[3];
    // d_in[4] = charge_w: provably no-op, unused
    float* out = (float*)d_out;

    // workspace (bf16 elements)
    unsigned short* xb     = (unsigned short*)d_ws;
    unsigned short* wqkvT  = xb + 4194304;        // [3072][1024]
    unsigned short* woutT  = wqkvT + 3145728;     // [1024][1024]
    unsigned short* qkv    = woutT + 1048576;     // [4096][3072]
    unsigned short* attn   = qkv + 12582912;      // [4096][1024]

    cvt_kernel<<<4096, 256, 0, stream>>>(x, xb, 4194304);
    tcvt_kernel<<<dim3(96, 32), 256, 0, stream>>>(w_qkv, wqkvT, 1024, 3072);
    tcvt_kernel<<<dim3(32, 32), 256, 0, stream>>>(w_out, woutT, 1024, 1024);

    // qkv = xb @ w_qkv (M=4096, N=3072, K=1024), bf16 out, q-columns pre-scaled
    gemm_kernel<true, true><<<dim3(24, 32), 256, 0, stream>>>(xb, wqkvT, (void*)qkv, 1024, 3072);

    // causal attention: 2 B x 16 H x 16 q-tiles
    attn2_kernel<<<512, 256, 0, stream>>>(qkv, attn);

    // out = attn @ w_out (M=4096, N=1024, K=1024), fp32 out
    gemm_kernel<false, false><<<dim3(8, 32), 256, 0, stream>>>(attn, woutT, (void*)out, 1024, 1024);
}

// Round 4
// 162.590 us; speedup vs baseline: 2.4624x; 1.0450x over previous
//
#include <hip/hip_runtime.h>
#include <stdint.h>

// Z9QATAttention: out = softmax_causal((x@Wqkv).q @ (x@Wqkv).k^T * D^-0.5) @ v @ Wout
// charge_bias: uniform pre-mask logit shift -> softmax-invariant -> no-op.
// mask == tril -> causal predicate. Softmax scale*log2e folded into q columns in GEMM1.

typedef __attribute__((ext_vector_type(4))) float f32x4;
typedef __attribute__((ext_vector_type(16))) float f32x16;
typedef __attribute__((ext_vector_type(8))) __bf16 bf16x8;
typedef __attribute__((ext_vector_type(8))) unsigned short ushort8;
typedef __attribute__((ext_vector_type(4))) unsigned short ushort4v;
typedef __attribute__((ext_vector_type(4))) unsigned int uint4v;

#define DEV __device__ __forceinline__

DEV unsigned short f32_to_bf16(float f) {
    union { float f; unsigned int u; } cv; cv.f = f;
    unsigned int u = cv.u;
    return (unsigned short)((u + 0x7FFFu + ((u >> 16) & 1u)) >> 16);
}

DEV bf16x8 load_bf16x8(const unsigned short* p) {
    ushort8 v = *(const ushort8*)p;
    return __builtin_bit_cast(bf16x8, v);
}

DEV unsigned cvt_pk_bf16(float lo, float hi) {
    unsigned r;
    asm("v_cvt_pk_bf16_f32 %0, %1, %2" : "=v"(r) : "v"(lo), "v"(hi));
    return r;
}

DEV void gload_lds16(const void* g, void* l) {
    __builtin_amdgcn_global_load_lds(
        (const __attribute__((address_space(1))) unsigned int*)g,
        (__attribute__((address_space(3))) unsigned int*)l, 16, 0, 0);
}

DEV f32x16 vzero16() {
    f32x16 v;
#pragma unroll
    for (int i = 0; i < 16; ++i) v[i] = 0.f;
    return v;
}

// ---------------- fp32 -> bf16 conversion ----------------
__global__ void cvt_kernel(const float* __restrict__ in, unsigned short* __restrict__ out, int n) {
    int i = (blockIdx.x * blockDim.x + threadIdx.x) * 4;
    if (i >= n) return;
    f32x4 v = *(const f32x4*)(in + i);
    ushort4v o;
    o[0] = f32_to_bf16(v[0]); o[1] = f32_to_bf16(v[1]);
    o[2] = f32_to_bf16(v[2]); o[3] = f32_to_bf16(v[3]);
    *(ushort4v*)(out + i) = o;
}

// ---------------- fp32 -> bf16 transpose: out[c][r] = bf16(in[r][c]) ----------------
__global__ __launch_bounds__(256) void tcvt_kernel(const float* __restrict__ in,
                                                   unsigned short* __restrict__ out,
                                                   int R, int Cn) {
    __shared__ float tl[32][33];
    const int tx = threadIdx.x & 31, ty = threadIdx.x >> 5;
    const int c0 = blockIdx.x * 32, r0 = blockIdx.y * 32;
#pragma unroll
    for (int rr = 0; rr < 4; ++rr) {
        int r = ty + rr * 8;
        tl[r][tx] = in[(size_t)(r0 + r) * Cn + c0 + tx];
    }
    __syncthreads();
#pragma unroll
    for (int rr = 0; rr < 4; ++rr) {
        int cc = ty + rr * 8;
        out[(size_t)(c0 + cc) * R + r0 + tx] = f32_to_bf16(tl[tx][cc]);
    }
}

// ---------------- bf16 MFMA GEMM (m97 pattern): C[M,N] = A[M,K] @ Bt[N,K]^T ----------------
template<bool OUT_BF16, bool SCALE_Q>
__global__ __launch_bounds__(256) void gemm_kernel(
    const unsigned short* __restrict__ A,
    const unsigned short* __restrict__ Bt,
    void* __restrict__ C, int K, int ldc)
{
    __shared__ __align__(16) unsigned short As[128 * 32];
    __shared__ __align__(16) unsigned short Bs[128 * 32];

    const int tid = threadIdx.x;
    const int lane = tid & 63;
    const int w = tid >> 6;
    const int wr = w >> 1, wc = w & 1;
    const int g = lane >> 4, ci = lane & 15;
    const int bx = blockIdx.x, by = blockIdx.y;

    f32x4 acc[4][4];
#pragma unroll
    for (int i = 0; i < 4; ++i)
#pragma unroll
        for (int j = 0; j < 4; ++j) acc[i][j] = f32x4{0.f, 0.f, 0.f, 0.f};

    for (int k0 = 0; k0 < K; k0 += 32) {
        __syncthreads();
#pragma unroll
        for (int i = 0; i < 2; ++i) {
            int off = i * 4096 + w * 1024 + lane * 16;   // byte offset in LDS tile
            int row = off >> 6;                           // 64B per row (BK=32 bf16)
            int cch = (off >> 4) & 3;
            gload_lds16(A  + (size_t)(by * 128 + row) * K + k0 + cch * 8,
                        (char*)As + i * 4096 + w * 1024);
            gload_lds16(Bt + (size_t)(bx * 128 + row) * K + k0 + cch * 8,
                        (char*)Bs + i * 4096 + w * 1024);
        }
        __syncthreads();

        bf16x8 af[4], bfr[4];
#pragma unroll
        for (int mf = 0; mf < 4; ++mf) af[mf]  = load_bf16x8(&As[(wr * 64 + mf * 16 + ci) * 32 + g * 8]);
#pragma unroll
        for (int nf = 0; nf < 4; ++nf) bfr[nf] = load_bf16x8(&Bs[(wc * 64 + nf * 16 + ci) * 32 + g * 8]);
#pragma unroll
        for (int mf = 0; mf < 4; ++mf)
#pragma unroll
            for (int nf = 0; nf < 4; ++nf)
                acc[mf][nf] = __builtin_amdgcn_mfma_f32_16x16x32_bf16(af[mf], bfr[nf], acc[mf][nf], 0, 0, 0);
    }

#pragma unroll
    for (int mf = 0; mf < 4; ++mf)
#pragma unroll
        for (int nf = 0; nf < 4; ++nf)
#pragma unroll
            for (int r = 0; r < 4; ++r) {
                int row = by * 128 + wr * 64 + mf * 16 + g * 4 + r;
                int col = bx * 128 + wc * 64 + nf * 16 + ci;
                float v = acc[mf][nf][r];
                if (SCALE_Q && col < 1024) v *= 0.1803368801f;  // D^-0.5 * log2(e)
                if (OUT_BF16)
                    ((unsigned short*)C)[(size_t)row * ldc + col] = f32_to_bf16(v);
                else
                    ((float*)C)[(size_t)row * ldc + col] = v;
            }
}

// ---------------- causal flash attention, 32x32x16 MFMA, depth-2 pipeline ----------------
// 4 waves x 32 q-rows (QBLK=128), KVBLK=64. K: triple-buffered LDS via global_load_lds
// (prefetch t+2), counted vmcnt + raw barriers (loads stay in flight across barriers).
// V: depth-2 reg staging (two reg sets) + double-buffered LDS (transposed, swizzled).
// LPT remap: heavy q-tiles dispatched first.
__global__ __launch_bounds__(256) void attn3_kernel(const unsigned short* __restrict__ qkv,
                                                    unsigned short* __restrict__ attn) {
    constexpr int T = 2048, HD3 = 3072, Cc = 1024;
    __shared__ __align__(16) unsigned short Ks[3][4096];  // [64 kv][64 d], col ^= (row&7)*8
    __shared__ __align__(16) unsigned short Vt[2][4096];  // [64 d][64 kv], col ^= ((d^(d>>3))&7)*8

    const int tid = threadIdx.x;
    const int lane = tid & 63;
    const int w = tid >> 6;
    const int l31 = lane & 31;
    const int hi = lane >> 5;

    const int bx = blockIdx.x;
    const int qb = 15 - (bx >> 5);       // LPT: heavy blocks (qb=15) dispatch first
    const int bh = bx & 31;
    const int h = bh & 15;
    const int b = bh >> 4;
    const int q0w = qb * 128 + w * 32;
    const int qrow = q0w + l31;
    const size_t base = (size_t)b * T * HD3;

    bf16x8 qf[4];   // B-operand: lane holds Q[qrow][t*16 + hi*8 + j] (q pre-scaled in GEMM1)
#pragma unroll
    for (int t = 0; t < 4; ++t)
        qf[t] = load_bf16x8(qkv + base + (size_t)qrow * HD3 + h * 64 + t * 16 + hi * 8);

    f32x16 acc0 = vzero16(), acc1 = vzero16();  // O^T: col=q(lane), row d = rr+8G+4hi (+32)
    float m = -3e38f, l = 0.f;
    const int nt = 2 * qb + 2;

    ushort8 vA0, vA1, vB0, vB1;
#define LOADV(tile, r0, r1) do { int kv0_ = (tile) * 64; \
    int rr0_ = tid >> 3, cc0_ = tid & 7; \
    r0 = *(const ushort8*)(qkv + base + (size_t)(kv0_ + rr0_) * HD3 + 2 * Cc + h * 64 + cc0_ * 8); \
    int c1_ = 256 + tid; int rr1_ = c1_ >> 3, cc1_ = c1_ & 7; \
    r1 = *(const ushort8*)(qkv + base + (size_t)(kv0_ + rr1_) * HD3 + 2 * Cc + h * 64 + cc1_ * 8); } while (0)

#define DMAK(tile, kb) do { int kv0_ = (tile) * 64; \
    _Pragma("unroll") for (int i_ = 0; i_ < 2; ++i_) { \
        int off_ = i_ * 4096 + w * 1024 + lane * 16; \
        int row_ = off_ >> 7; \
        int csw_ = ((lane & 7) * 8) ^ ((row_ & 7) * 8); \
        gload_lds16(qkv + base + (size_t)(kv0_ + row_) * HD3 + Cc + h * 64 + csw_, \
                    (void*)(((char*)&Ks[kb][0]) + i_ * 4096 + w * 1024)); } } while (0)

#define WRITEV(vb, r0, r1) do { \
    _Pragma("unroll") for (int i_ = 0; i_ < 2; ++i_) { \
        int c_ = i_ * 256 + tid; int row_ = c_ >> 3, cc_ = c_ & 7; \
        ushort8 v_ = i_ ? r1 : r0; \
        _Pragma("unroll") for (int j_ = 0; j_ < 8; ++j_) { \
            int d_ = cc_ * 8 + j_; \
            int sw_ = ((d_ ^ (d_ >> 3)) & 7) * 8; \
            Vt[vb][d_ * 64 + (row_ ^ sw_)] = v_[j_]; } } } while (0)

    // prologue: tile 0 fully staged; tile 1 in flight
    LOADV(0, vA0, vA1);
    DMAK(0, 0);
    asm volatile("s_waitcnt vmcnt(0)" ::: "memory");
    __builtin_amdgcn_sched_barrier(0);
    WRITEV(0, vA0, vA1);
    LOADV(1, vB0, vB1);
    DMAK(1, 1);
    asm volatile("s_waitcnt lgkmcnt(0)" ::: "memory");
    __builtin_amdgcn_sched_barrier(0);
    __builtin_amdgcn_s_barrier();
    __builtin_amdgcn_sched_barrier(0);

    for (int t = 0; t < nt; ++t) {
        const int kv0 = t * 64;
        const int kcur = t % 3;
        const int vcur = t & 1;
        const bool act = (kv0 <= q0w + 31);
        const bool pre2 = (t + 2) < nt;

        if (pre2) {   // issue prefetch for tile t+2 (V->regs, K->LDS buf (t+2)%3)
            if (t & 1) LOADV(t + 2, vB0, vB1); else LOADV(t + 2, vA0, vA1);
            DMAK(t + 2, (t + 2) % 3);
        }

        f32x16 s0 = vzero16(), s1 = vzero16();
        bf16x8 pf[4];
        if (act) {
            const bool st1_ok = (kv0 + 32 <= q0w + 31);
            __builtin_amdgcn_s_setprio(1);
#pragma unroll
            for (int tt = 0; tt < 4; ++tt) {  // st = 0
                int row = l31;
                int idx = kcur * 4096 + row * 64 + ((tt * 16 + hi * 8) ^ ((row & 7) * 8));
                s0 = __builtin_amdgcn_mfma_f32_32x32x16_bf16(load_bf16x8(&Ks[0][idx]), qf[tt], s0, 0, 0, 0);
            }
            if (st1_ok) {
#pragma unroll
                for (int tt = 0; tt < 4; ++tt) {  // st = 1
                    int row = 32 + l31;
                    int idx = kcur * 4096 + row * 64 + ((tt * 16 + hi * 8) ^ ((row & 7) * 8));
                    s1 = __builtin_amdgcn_mfma_f32_32x32x16_bf16(load_bf16x8(&Ks[0][idx]), qf[tt], s1, 0, 0, 0);
                }
            }
            __builtin_amdgcn_s_setprio(0);
            const bool needmask = (kv0 + 63 > q0w);
            if (needmask) {
#pragma unroll
                for (int G = 0; G < 4; ++G)
#pragma unroll
                    for (int rr = 0; rr < 4; ++rr) {
                        int kvb = kv0 + 8 * G + 4 * hi + rr;  // kv of C-reg (crow formula, HW-verified)
                        s0[G * 4 + rr] = (kvb      <= qrow) ? s0[G * 4 + rr] : -3e38f;
                        s1[G * 4 + rr] = (kvb + 32 <= qrow) ? s1[G * 4 + rr] : -3e38f;
                    }
            }
            float pmax = -3e38f;
#pragma unroll
            for (int i = 0; i < 16; ++i) pmax = fmaxf(pmax, fmaxf(s0[i], s1[i]));
            pmax = fmaxf(pmax, __shfl_xor(pmax, 32));
            // defer-max (T13): skip O/l rescale while pmax - m <= 11.5 (log2 domain)
            if (!__all(pmax - m <= 11.5f)) {
                float mnew = fmaxf(m, pmax);
                float alpha = exp2f(m - mnew);
                m = mnew;
                l *= alpha;
#pragma unroll
                for (int i = 0; i < 16; ++i) { acc0[i] *= alpha; acc1[i] *= alpha; }
            }
            float rs = 0.f;
#pragma unroll
            for (int i = 0; i < 16; ++i) {
                s0[i] = exp2f(s0[i] - m);
                s1[i] = exp2f(s1[i] - m);
                rs += s0[i] + s1[i];
            }
            rs += __shfl_xor(rs, 32);
            l += rs;

            // P -> B-fragments, fully in-register (cvt_pk + lane<->lane+32 swap)
            unsigned pk0[4][2], pk1[4][2];
#pragma unroll
            for (int G = 0; G < 4; ++G) {
                pk0[G][0] = cvt_pk_bf16(s0[G * 4 + 0], s0[G * 4 + 1]);
                pk0[G][1] = cvt_pk_bf16(s0[G * 4 + 2], s0[G * 4 + 3]);
                pk1[G][0] = cvt_pk_bf16(s1[G * 4 + 0], s1[G * 4 + 1]);
                pk1[G][1] = cvt_pk_bf16(s1[G * 4 + 2], s1[G * 4 + 3]);
            }
#pragma unroll
            for (int tf = 0; tf < 4; ++tf) {
                const int kb = tf & 1;
                unsigned sA0, sA1, sB0, sB1;
                if (tf < 2) { sA0 = pk0[2 * kb][0]; sA1 = pk0[2 * kb][1]; sB0 = pk0[2 * kb + 1][0]; sB1 = pk0[2 * kb + 1][1]; }
                else        { sA0 = pk1[2 * kb][0]; sA1 = pk1[2 * kb][1]; sB0 = pk1[2 * kb + 1][0]; sB1 = pk1[2 * kb + 1][1]; }
                unsigned sd0 = hi ? sA0 : sB0, sd1 = hi ? sA1 : sB1;
                unsigned rc0 = (unsigned)__shfl_xor((int)sd0, 32);
                unsigned rc1 = (unsigned)__shfl_xor((int)sd1, 32);
                uint4v u;
                u[0] = hi ? rc0 : sA0;  u[1] = hi ? rc1 : sA1;   // k = hi*8 + 0..3
                u[2] = hi ? sB0 : rc0;  u[3] = hi ? sB1 : rc1;   // k = hi*8 + 4..7
                pf[tf] = __builtin_bit_cast(bf16x8, u);
            }
        }

        if (t + 1 < nt) {   // write V(t+1) into the other LDS buffer (regs loaded 1 iter ago)
            if (t & 1) WRITEV(vcur ^ 1, vA0, vA1); else WRITEV(vcur ^ 1, vB0, vB1);
        }

        if (act) {
            __builtin_amdgcn_s_setprio(1);
#pragma unroll
            for (int tt = 0; tt < 4; ++tt) {
                {
                    int d = l31, sw = ((d ^ (d >> 3)) & 7) * 8;
                    bf16x8 vf = load_bf16x8(&Vt[vcur][d * 64 + ((tt * 16 + hi * 8) ^ sw)]);
                    acc0 = __builtin_amdgcn_mfma_f32_32x32x16_bf16(vf, pf[tt], acc0, 0, 0, 0);
                }
                {
                    int d = 32 + l31, sw = ((d ^ (d >> 3)) & 7) * 8;
                    bf16x8 vf = load_bf16x8(&Vt[vcur][d * 64 + ((tt * 16 + hi * 8) ^ sw)]);
                    acc1 = __builtin_amdgcn_mfma_f32_32x32x16_bf16(vf, pf[tt], acc1, 0, 0, 0);
                }
            }
            __builtin_amdgcn_s_setprio(0);
        }

        // counted-vmcnt barrier: K(t+1) (oldest of the <=6 outstanding after the V-reg wait)
        // must have landed; with prefetch(t+2) in flight that is vmcnt(4), else full drain.
        if (pre2) asm volatile("s_waitcnt vmcnt(4) lgkmcnt(0)" ::: "memory");
        else      asm volatile("s_waitcnt vmcnt(0) lgkmcnt(0)" ::: "memory");
        __builtin_amdgcn_sched_barrier(0);
        __builtin_amdgcn_s_barrier();
        __builtin_amdgcn_sched_barrier(0);
    }

    const float invl = 1.0f / l;
    const size_t ob = (size_t)b * T * Cc + (size_t)qrow * Cc + h * 64;
#pragma unroll
    for (int G = 0; G < 4; ++G) {
        ushort4v o0, o1;
#pragma unroll
        for (int rr = 0; rr < 4; ++rr) {
            o0[rr] = f32_to_bf16(acc0[G * 4 + rr] * invl);
            o1[rr] = f32_to_bf16(acc1[G * 4 + rr] * invl);
        }
        int d0 = 8 * G + 4 * hi;
        *(ushort4v*)(attn + ob + d0) = o0;
        *(ushort4v*)(attn + ob + 32 + d0) = o1;
    }
#undef LOADV
#undef DMAK
#undef WRITEV
}

extern "C" void kernel_launch(void* const* d_in, const int* in_sizes, int n_in,
                              void* d_out, int out_size, void* d_ws, size_t ws_size,
                              hipStream_t stream) {
    const float* x     = (const float*)d_in[0];
    // d_in[1] = mask (tril -> causal predicate), unused
    const float* w_qkv = (const float*)d_in[2];
    const float* w_out = (const float*)d_in[3];
    // d_in[4] = charge_w: provably no-op, unused
    float* out = (float*)d_out;

    // workspace (bf16 elements)
    unsigned short* xb     = (unsigned short*)d_ws;
    unsigned short* wqkvT  = xb + 4194304;        // [3072][1024]
    unsigned short* woutT  = wqkvT + 3145728;     // [1024][1024]
    unsigned short* qkv    = woutT + 1048576;     // [4096][3072]
    unsigned short* attn   = qkv + 12582912;      // [4096][1024]

    cvt_kernel<<<4096, 256, 0, stream>>>(x, xb, 4194304);
    tcvt_kernel<<<dim3(96, 32), 256, 0, stream>>>(w_qkv, wqkvT, 1024, 3072);
    tcvt_kernel<<<dim3(32, 32), 256, 0, stream>>>(w_out, woutT, 1024, 1024);

    // qkv = xb @ w_qkv (M=4096, N=3072, K=1024), bf16 out, q-columns pre-scaled
    gemm_kernel<true, true><<<dim3(24, 32), 256, 0, stream>>>(xb, wqkvT, (void*)qkv, 1024, 3072);

    // causal attention: 2 B x 16 H x 16 q-tiles (LPT-remapped)
    attn3_kernel<<<512, 256, 0, stream>>>(qkv, attn);

    // out = attn @ w_out (M=4096, N=1024, K=1024), fp32 out
    gemm_kernel<false, false><<<dim3(8, 32), 256, 0, stream>>>(attn, woutT, (void*)out, 1024, 1024);
}

// Round 6
// 156.019 us; speedup vs baseline: 2.5661x; 1.0421x over previous
//
#include <hip/hip_runtime.h>
#include <stdint.h>

// Z9QATAttention: out = softmax_causal((x@Wqkv).q @ (x@Wqkv).k^T * D^-0.5) @ v @ Wout
// charge_bias: uniform pre-mask logit shift -> softmax-invariant -> no-op.
// mask == tril -> causal predicate. Softmax scale*log2e folded into q columns in GEMM1.

typedef __attribute__((ext_vector_type(4))) float f32x4;
typedef __attribute__((ext_vector_type(16))) float f32x16;
typedef __attribute__((ext_vector_type(8))) __bf16 bf16x8;
typedef __attribute__((ext_vector_type(8))) unsigned short ushort8;
typedef __attribute__((ext_vector_type(4))) unsigned short ushort4v;
typedef __attribute__((ext_vector_type(4))) unsigned int uint4v;

#define DEV __device__ __forceinline__

DEV unsigned short f32_to_bf16(float f) {
    union { float f; unsigned int u; } cv; cv.f = f;
    unsigned int u = cv.u;
    return (unsigned short)((u + 0x7FFFu + ((u >> 16) & 1u)) >> 16);
}

DEV bf16x8 load_bf16x8(const unsigned short* p) {
    ushort8 v = *(const ushort8*)p;
    return __builtin_bit_cast(bf16x8, v);
}

DEV unsigned cvt_pk_bf16(float lo, float hi) {
    unsigned r;
    asm("v_cvt_pk_bf16_f32 %0, %1, %2" : "=v"(r) : "v"(lo), "v"(hi));
    return r;
}

DEV void gload_lds16(const void* g, void* l) {
    __builtin_amdgcn_global_load_lds(
        (const __attribute__((address_space(1))) unsigned int*)g,
        (__attribute__((address_space(3))) unsigned int*)l, 16, 0, 0);
}

DEV f32x16 vzero16() {
    f32x16 v;
#pragma unroll
    for (int i = 0; i < 16; ++i) v[i] = 0.f;
    return v;
}

// tree reductions over the 32 S values (depth 5 instead of 31-deep chains)
DEV float tmax32(const f32x16& a, const f32x16& b) {
    float m[16];
#pragma unroll
    for (int i = 0; i < 16; ++i) m[i] = fmaxf(a[i], b[i]);
#pragma unroll
    for (int st = 8; st > 0; st >>= 1)
#pragma unroll
        for (int i = 0; i < 8; ++i) if (i < st) m[i] = fmaxf(m[i], m[i + st]);
    return m[0];
}
DEV float tsum32(const f32x16& a, const f32x16& b) {
    float m[16];
#pragma unroll
    for (int i = 0; i < 16; ++i) m[i] = a[i] + b[i];
#pragma unroll
    for (int st = 8; st > 0; st >>= 1)
#pragma unroll
        for (int i = 0; i < 8; ++i) if (i < st) m[i] = m[i] + m[i + st];
    return m[0];
}

// ---------------- fp32 -> bf16 conversion ----------------
__global__ void cvt_kernel(const float* __restrict__ in, unsigned short* __restrict__ out, int n) {
    int i = (blockIdx.x * blockDim.x + threadIdx.x) * 4;
    if (i >= n) return;
    f32x4 v = *(const f32x4*)(in + i);
    ushort4v o;
    o[0] = f32_to_bf16(v[0]); o[1] = f32_to_bf16(v[1]);
    o[2] = f32_to_bf16(v[2]); o[3] = f32_to_bf16(v[3]);
    *(ushort4v*)(out + i) = o;
}

// ---------------- fp32 -> bf16 transpose: out[c][r] = bf16(in[r][c]) ----------------
__global__ __launch_bounds__(256) void tcvt_kernel(const float* __restrict__ in,
                                                   unsigned short* __restrict__ out,
                                                   int R, int Cn) {
    __shared__ float tl[32][33];
    const int tx = threadIdx.x & 31, ty = threadIdx.x >> 5;
    const int c0 = blockIdx.x * 32, r0 = blockIdx.y * 32;
#pragma unroll
    for (int rr = 0; rr < 4; ++rr) {
        int r = ty + rr * 8;
        tl[r][tx] = in[(size_t)(r0 + r) * Cn + c0 + tx];
    }
    __syncthreads();
#pragma unroll
    for (int rr = 0; rr < 4; ++rr) {
        int cc = ty + rr * 8;
        out[(size_t)(c0 + cc) * R + r0 + tx] = f32_to_bf16(tl[tx][cc]);
    }
}

// ---------------- bf16 MFMA GEMM, 2-phase double-buffered: C = A @ Bt^T ----------------
template<bool OUT_BF16, bool SCALE_Q>
__global__ __launch_bounds__(256) void gemm_kernel(
    const unsigned short* __restrict__ A,
    const unsigned short* __restrict__ Bt,
    void* __restrict__ C, int K, int ldc)
{
    __shared__ __align__(16) unsigned short As[2][4096];
    __shared__ __align__(16) unsigned short Bs[2][4096];

    const int tid = threadIdx.x;
    const int lane = tid & 63;
    const int w = tid >> 6;
    const int wr = w >> 1, wc = w & 1;
    const int g = lane >> 4, ci = lane & 15;
    const int bx = blockIdx.x, by = blockIdx.y;
    const int soff = w * 1024 + lane * 16;       // staging byte offset (i=0)
    const int srow = soff >> 6;                  // 64B (BK=32 bf16) per row
    const int scch = (soff >> 4) & 3;

#define GSTAGE(buf, k0_) do { \
    _Pragma("unroll") for (int i_ = 0; i_ < 2; ++i_) { \
        int row_ = srow + i_ * 64; \
        gload_lds16(A  + (size_t)(by * 128 + row_) * K + (k0_) + scch * 8, \
                    (char*)As[buf] + i_ * 4096 + w * 1024); \
        gload_lds16(Bt + (size_t)(bx * 128 + row_) * K + (k0_) + scch * 8, \
                    (char*)Bs[buf] + i_ * 4096 + w * 1024); } } while (0)

    f32x4 acc[4][4];
#pragma unroll
    for (int i = 0; i < 4; ++i)
#pragma unroll
        for (int j = 0; j < 4; ++j) acc[i][j] = f32x4{0.f, 0.f, 0.f, 0.f};

    GSTAGE(0, 0);
    asm volatile("s_waitcnt vmcnt(0)" ::: "memory");
    __builtin_amdgcn_sched_barrier(0);
    __builtin_amdgcn_s_barrier();
    __builtin_amdgcn_sched_barrier(0);

    const int nk = K >> 5;
    for (int kt = 0; kt < nk; ++kt) {
        const int cur = kt & 1;
        if (kt + 1 < nk) GSTAGE(cur ^ 1, (kt + 1) << 5);   // issue next stage first

        bf16x8 af[4], bfr[4];
#pragma unroll
        for (int mf = 0; mf < 4; ++mf) af[mf]  = load_bf16x8(&As[cur][(wr * 64 + mf * 16 + ci) * 32 + g * 8]);
#pragma unroll
        for (int nf = 0; nf < 4; ++nf) bfr[nf] = load_bf16x8(&Bs[cur][(wc * 64 + nf * 16 + ci) * 32 + g * 8]);
#pragma unroll
        for (int mf = 0; mf < 4; ++mf)
#pragma unroll
            for (int nf = 0; nf < 4; ++nf)
                acc[mf][nf] = __builtin_amdgcn_mfma_f32_16x16x32_bf16(af[mf], bfr[nf], acc[mf][nf], 0, 0, 0);

        asm volatile("s_waitcnt vmcnt(0) lgkmcnt(0)" ::: "memory");
        __builtin_amdgcn_sched_barrier(0);
        __builtin_amdgcn_s_barrier();
        __builtin_amdgcn_sched_barrier(0);
    }
#undef GSTAGE

#pragma unroll
    for (int mf = 0; mf < 4; ++mf)
#pragma unroll
        for (int nf = 0; nf < 4; ++nf)
#pragma unroll
            for (int r = 0; r < 4; ++r) {
                int row = by * 128 + wr * 64 + mf * 16 + g * 4 + r;
                int col = bx * 128 + wc * 64 + nf * 16 + ci;
                float v = acc[mf][nf][r];
                if (SCALE_Q && col < 1024) v *= 0.1803368801f;  // D^-0.5 * log2(e)
                if (OUT_BF16)
                    ((unsigned short*)C)[(size_t)row * ldc + col] = f32_to_bf16(v);
                else
                    ((float*)C)[(size_t)row * ldc + col] = v;
            }
}

// ---------------- causal flash attention, 32x32x16 MFMA, fixed depth-2 pipeline ----------------
// WRITEV at iteration top (its implicit vmem wait only covers 1-tile-old loads); explicit
// vmcnt(4) at the barrier keeps the t+2 prefetch in flight across iterations.
__global__ __launch_bounds__(256) void attn4_kernel(const unsigned short* __restrict__ qkv,
                                                    unsigned short* __restrict__ attn) {
    constexpr int T = 2048, HD3 = 3072, Cc = 1024;
    __shared__ __align__(16) unsigned short Ks[3][4096];  // [64 kv][64 d], col ^= (row&7)*8
    __shared__ __align__(16) unsigned short Vt[2][4096];  // [64 d][64 kv], col ^= ((d^(d>>3))&7)*8

    const int tid = threadIdx.x;
    const int lane = tid & 63;
    const int w = tid >> 6;
    const int l31 = lane & 31;
    const int hi = lane >> 5;

    const int bx = blockIdx.x;
    // complementary pairing: co-resident blocks bx and bx+256 get qb and 15-qb (constant sum)
    const int qb = (bx < 256) ? (15 - (bx >> 5)) : ((bx - 256) >> 5);
    const int bh = bx & 31;
    const int h = bh & 15;
    const int b = bh >> 4;
    const int q0w = qb * 128 + w * 32;
    const int qrow = q0w + l31;
    const size_t base = (size_t)b * T * HD3;

    bf16x8 qf[4];   // B-operand: lane holds Q[qrow][t*16 + hi*8 + j] (q pre-scaled in GEMM1)
#pragma unroll
    for (int t = 0; t < 4; ++t)
        qf[t] = load_bf16x8(qkv + base + (size_t)qrow * HD3 + h * 64 + t * 16 + hi * 8);

    f32x16 acc0 = vzero16(), acc1 = vzero16();  // O^T: col=q(lane), row d = rr+8G+4hi (+32)
    float m = -3e38f, l = 0.f;
    const int nt = 2 * qb + 2;

    ushort8 vA0, vA1, vB0, vB1;
#define LOADV(tile, r0, r1) do { int kv0_ = (tile) * 64; \
    int rr0_ = tid >> 3, cc0_ = tid & 7; \
    r0 = *(const ushort8*)(qkv + base + (size_t)(kv0_ + rr0_) * HD3 + 2 * Cc + h * 64 + cc0_ * 8); \
    int c1_ = 256 + tid; int rr1_ = c1_ >> 3, cc1_ = c1_ & 7; \
    r1 = *(const ushort8*)(qkv + base + (size_t)(kv0_ + rr1_) * HD3 + 2 * Cc + h * 64 + cc1_ * 8); } while (0)

#define DMAK(tile, kb) do { int kv0_ = (tile) * 64; \
    _Pragma("unroll") for (int i_ = 0; i_ < 2; ++i_) { \
        int off_ = i_ * 4096 + w * 1024 + lane * 16; \
        int row_ = off_ >> 7; \
        int csw_ = ((lane & 7) * 8) ^ ((row_ & 7) * 8); \
        gload_lds16(qkv + base + (size_t)(kv0_ + row_) * HD3 + Cc + h * 64 + csw_, \
                    (void*)(((char*)&Ks[kb][0]) + i_ * 4096 + w * 1024)); } } while (0)

#define WRITEV(vb, r0, r1) do { \
    _Pragma("unroll") for (int i_ = 0; i_ < 2; ++i_) { \
        int c_ = i_ * 256 + tid; int row_ = c_ >> 3, cc_ = c_ & 7; \
        ushort8 v_ = i_ ? r1 : r0; \
        _Pragma("unroll") for (int j_ = 0; j_ < 8; ++j_) { \
            int d_ = cc_ * 8 + j_; \
            int sw_ = ((d_ ^ (d_ >> 3)) & 7) * 8; \
            Vt[vb][d_ * 64 + (row_ ^ sw_)] = v_[j_]; } } } while (0)

    // prologue: tile 0 fully staged; tile 1 in flight
    LOADV(0, vA0, vA1);
    DMAK(0, 0);
    asm volatile("s_waitcnt vmcnt(0)" ::: "memory");
    __builtin_amdgcn_sched_barrier(0);
    WRITEV(0, vA0, vA1);
    LOADV(1, vB0, vB1);
    DMAK(1, 1);
    asm volatile("s_waitcnt lgkmcnt(0)" ::: "memory");
    __builtin_amdgcn_sched_barrier(0);
    __builtin_amdgcn_s_barrier();
    __builtin_amdgcn_sched_barrier(0);

    for (int t = 0; t < nt; ++t) {
        const int kv0 = t * 64;
        const int kcur = t % 3;
        const int vcur = t & 1;
        const bool act = (kv0 <= q0w + 31);
        const bool pre2 = (t + 2) < nt;

        // 1. write V(t+1) to LDS (regs 1 tile old -> any implicit vmem wait here is free)
        if (t + 1 < nt) {
            if (t & 1) WRITEV(vcur ^ 1, vA0, vA1); else WRITEV(vcur ^ 1, vB0, vB1);
        }
        // 2. issue prefetch for tile t+2 (V->regs, K->LDS buf (t+2)%3)
        if (pre2) {
            if (t & 1) LOADV(t + 2, vB0, vB1); else LOADV(t + 2, vA0, vA1);
            DMAK(t + 2, (t + 2) % 3);
        }

        if (act) {
            f32x16 s0 = vzero16(), s1 = vzero16();
            bf16x8 pf[4];
            const bool st1_ok = (kv0 + 32 <= q0w + 31);
            __builtin_amdgcn_s_setprio(1);
#pragma unroll
            for (int tt = 0; tt < 4; ++tt) {  // st = 0
                int row = l31;
                int idx = kcur * 4096 + row * 64 + ((tt * 16 + hi * 8) ^ ((row & 7) * 8));
                s0 = __builtin_amdgcn_mfma_f32_32x32x16_bf16(load_bf16x8(&Ks[0][idx]), qf[tt], s0, 0, 0, 0);
            }
            if (st1_ok) {
#pragma unroll
                for (int tt = 0; tt < 4; ++tt) {  // st = 1
                    int row = 32 + l31;
                    int idx = kcur * 4096 + row * 64 + ((tt * 16 + hi * 8) ^ ((row & 7) * 8));
                    s1 = __builtin_amdgcn_mfma_f32_32x32x16_bf16(load_bf16x8(&Ks[0][idx]), qf[tt], s1, 0, 0, 0);
                }
            }
            __builtin_amdgcn_s_setprio(0);
            const bool needmask = (kv0 + 63 > q0w);
            if (needmask) {
#pragma unroll
                for (int G = 0; G < 4; ++G)
#pragma unroll
                    for (int rr = 0; rr < 4; ++rr) {
                        int kvb = kv0 + 8 * G + 4 * hi + rr;  // kv of C-reg (crow formula, HW-verified)
                        s0[G * 4 + rr] = (kvb      <= qrow) ? s0[G * 4 + rr] : -3e38f;
                        s1[G * 4 + rr] = (kvb + 32 <= qrow) ? s1[G * 4 + rr] : -3e38f;
                    }
            }
            float pmax = tmax32(s0, s1);
            pmax = fmaxf(pmax, __shfl_xor(pmax, 32));   // HW-verified exchange (rounds 3-4)
            // defer-max (T13): skip O/l rescale while pmax - m <= 11.5 (log2 domain)
            if (!__all(pmax - m <= 11.5f)) {
                float mnew = fmaxf(m, pmax);
                float alpha = exp2f(m - mnew);
                m = mnew;
                l *= alpha;
#pragma unroll
                for (int i = 0; i < 16; ++i) { acc0[i] *= alpha; acc1[i] *= alpha; }
            }
#pragma unroll
            for (int i = 0; i < 16; ++i) {
                s0[i] = exp2f(s0[i] - m);
                s1[i] = exp2f(s1[i] - m);
            }

            // P -> B-fragments (cvt_pk + lane<->lane+32 exchange, HW-verified construction)
            unsigned pk0[4][2], pk1[4][2];
#pragma unroll
            for (int G = 0; G < 4; ++G) {
                pk0[G][0] = cvt_pk_bf16(s0[G * 4 + 0], s0[G * 4 + 1]);
                pk0[G][1] = cvt_pk_bf16(s0[G * 4 + 2], s0[G * 4 + 3]);
                pk1[G][0] = cvt_pk_bf16(s1[G * 4 + 0], s1[G * 4 + 1]);
                pk1[G][1] = cvt_pk_bf16(s1[G * 4 + 2], s1[G * 4 + 3]);
            }
#pragma unroll
            for (int tf = 0; tf < 4; ++tf) {
                const int kb = tf & 1;
                unsigned sA0, sA1, sB0, sB1;
                if (tf < 2) { sA0 = pk0[2 * kb][0]; sA1 = pk0[2 * kb][1]; sB0 = pk0[2 * kb + 1][0]; sB1 = pk0[2 * kb + 1][1]; }
                else        { sA0 = pk1[2 * kb][0]; sA1 = pk1[2 * kb][1]; sB0 = pk1[2 * kb + 1][0]; sB1 = pk1[2 * kb + 1][1]; }
                unsigned sd0 = hi ? sA0 : sB0, sd1 = hi ? sA1 : sB1;
                unsigned rc0 = (unsigned)__shfl_xor((int)sd0, 32);
                unsigned rc1 = (unsigned)__shfl_xor((int)sd1, 32);
                uint4v u;
                u[0] = hi ? rc0 : sA0;  u[1] = hi ? rc1 : sA1;   // k = hi*8 + 0..3
                u[2] = hi ? sB0 : rc0;  u[3] = hi ? sB1 : rc1;   // k = hi*8 + 4..7
                pf[tf] = __builtin_bit_cast(bf16x8, u);
            }

            __builtin_amdgcn_s_setprio(1);
#pragma unroll
            for (int tt = 0; tt < 4; ++tt) {
                {
                    int d = l31, sw = ((d ^ (d >> 3)) & 7) * 8;
                    bf16x8 vf = load_bf16x8(&Vt[vcur][d * 64 + ((tt * 16 + hi * 8) ^ sw)]);
                    acc0 = __builtin_amdgcn_mfma_f32_32x32x16_bf16(vf, pf[tt], acc0, 0, 0, 0);
                }
                {
                    int d = 32 + l31, sw = ((d ^ (d >> 3)) & 7) * 8;
                    bf16x8 vf = load_bf16x8(&Vt[vcur][d * 64 + ((tt * 16 + hi * 8) ^ sw)]);
                    acc1 = __builtin_amdgcn_mfma_f32_32x32x16_bf16(vf, pf[tt], acc1, 0, 0, 0);
                }
            }
            __builtin_amdgcn_s_setprio(0);

            // row-sum + l update off the PV critical path
            float rsum = tsum32(s0, s1);
            l += rsum + __shfl_xor(rsum, 32);
        }

        // counted-vmcnt barrier: guarantee K(t+1) landed, keep t+2 prefetch in flight
        if (pre2) asm volatile("s_waitcnt vmcnt(4) lgkmcnt(0)" ::: "memory");
        else      asm volatile("s_waitcnt vmcnt(0) lgkmcnt(0)" ::: "memory");
        __builtin_amdgcn_sched_barrier(0);
        __builtin_amdgcn_s_barrier();
        __builtin_amdgcn_sched_barrier(0);
    }

    const float invl = 1.0f / l;
    const size_t ob = (size_t)b * T * Cc + (size_t)qrow * Cc + h * 64;
#pragma unroll
    for (int G = 0; G < 4; ++G) {
        ushort4v o0, o1;
#pragma unroll
        for (int rr = 0; rr < 4; ++rr) {
            o0[rr] = f32_to_bf16(acc0[G * 4 + rr] * invl);
            o1[rr] = f32_to_bf16(acc1[G * 4 + rr] * invl);
        }
        int d0 = 8 * G + 4 * hi;
        *(ushort4v*)(attn + ob + d0) = o0;
        *(ushort4v*)(attn + ob + 32 + d0) = o1;
    }
#undef LOADV
#undef DMAK
#undef WRITEV
}

extern "C" void kernel_launch(void* const* d_in, const int* in_sizes, int n_in,
                              void* d_out, int out_size, void* d_ws, size_t ws_size,
                              hipStream_t stream) {
    const float* x     = (const float*)d_in[0];
    // d_in[1] = mask (tril -> causal predicate), unused
    const float* w_qkv = (const float*)d_in[2];
    const float* w_out = (const float*)d_in[3];
    // d_in[4] = charge_w: provably no-op, unused
    float* out = (float*)d_out;

    // workspace (bf16 elements)
    unsigned short* xb     = (unsigned short*)d_ws;
    unsigned short* wqkvT  = xb + 4194304;        // [3072][1024]
    unsigned short* woutT  = wqkvT + 3145728;     // [1024][1024]
    unsigned short* qkv    = woutT + 1048576;     // [4096][3072]
    unsigned short* attn   = qkv + 12582912;      // [4096][1024]

    cvt_kernel<<<4096, 256, 0, stream>>>(x, xb, 4194304);
    tcvt_kernel<<<dim3(96, 32), 256, 0, stream>>>(w_qkv, wqkvT, 1024, 3072);
    tcvt_kernel<<<dim3(32, 32), 256, 0, stream>>>(w_out, woutT, 1024, 1024);

    // qkv = xb @ w_qkv (M=4096, N=3072, K=1024), bf16 out, q-columns pre-scaled
    gemm_kernel<true, true><<<dim3(24, 32), 256, 0, stream>>>(xb, wqkvT, (void*)qkv, 1024, 3072);

    // causal attention: 2 B x 16 H x 16 q-tiles (complementary-pair remap)
    attn4_kernel<<<512, 256, 0, stream>>>(qkv, attn);

    // out = attn @ w_out (M=4096, N=1024, K=1024), fp32 out
    gemm_kernel<false, false><<<dim3(8, 32), 256, 0, stream>>>(attn, woutT, (void*)out, 1024, 1024);
}

// Round 7
// 139.848 us; speedup vs baseline: 2.8628x; 1.1156x over previous
//
#include <hip/hip_runtime.h>
#include <stdint.h>

// Z9QATAttention: out = softmax_causal((x@Wqkv).q @ (x@Wqkv).k^T * D^-0.5) @ v @ Wout
// charge_bias: uniform pre-mask logit shift -> softmax-invariant -> no-op.
// mask == tril -> causal predicate. Softmax scale*log2e folded into q columns in GEMM1.
// Round 7: kv-split flash decomposition (768 near-equal blocks, LPT order) + combine.

typedef __attribute__((ext_vector_type(4))) float f32x4;
typedef __attribute__((ext_vector_type(16))) float f32x16;
typedef __attribute__((ext_vector_type(8))) __bf16 bf16x8;
typedef __attribute__((ext_vector_type(8))) unsigned short ushort8;
typedef __attribute__((ext_vector_type(4))) unsigned short ushort4v;
typedef __attribute__((ext_vector_type(4))) unsigned int uint4v;

#define DEV __device__ __forceinline__

DEV unsigned short f32_to_bf16(float f) {
    union { float f; unsigned int u; } cv; cv.f = f;
    unsigned int u = cv.u;
    return (unsigned short)((u + 0x7FFFu + ((u >> 16) & 1u)) >> 16);
}

DEV float bf16_to_f32(unsigned short u) {
    union { unsigned int i; float f; } cv; cv.i = ((unsigned int)u) << 16;
    return cv.f;
}

DEV bf16x8 load_bf16x8(const unsigned short* p) {
    ushort8 v = *(const ushort8*)p;
    return __builtin_bit_cast(bf16x8, v);
}

DEV unsigned cvt_pk_bf16(float lo, float hi) {
    unsigned r;
    asm("v_cvt_pk_bf16_f32 %0, %1, %2" : "=v"(r) : "v"(lo), "v"(hi));
    return r;
}

DEV void gload_lds16(const void* g, void* l) {
    __builtin_amdgcn_global_load_lds(
        (const __attribute__((address_space(1))) unsigned int*)g,
        (__attribute__((address_space(3))) unsigned int*)l, 16, 0, 0);
}

DEV f32x16 vzero16() {
    f32x16 v;
#pragma unroll
    for (int i = 0; i < 16; ++i) v[i] = 0.f;
    return v;
}

// tree reductions over the 32 S values (depth 5 instead of 31-deep chains)
DEV float tmax32(const f32x16& a, const f32x16& b) {
    float m[16];
#pragma unroll
    for (int i = 0; i < 16; ++i) m[i] = fmaxf(a[i], b[i]);
#pragma unroll
    for (int st = 8; st > 0; st >>= 1)
#pragma unroll
        for (int i = 0; i < 8; ++i) if (i < st) m[i] = fmaxf(m[i], m[i + st]);
    return m[0];
}
DEV float tsum32(const f32x16& a, const f32x16& b) {
    float m[16];
#pragma unroll
    for (int i = 0; i < 16; ++i) m[i] = a[i] + b[i];
#pragma unroll
    for (int st = 8; st > 0; st >>= 1)
#pragma unroll
        for (int i = 0; i < 8; ++i) if (i < st) m[i] = m[i] + m[i + st];
    return m[0];
}

// LPT work table: 24 items per (b,h), j-major dispatch so heaviest run first.
// qtab = q-tile index; ctab: 255 = full q-tile, 0 = kv chunk [0,q+1), 1 = chunk [q+1,2q+2).
__device__ __constant__ unsigned char qtab[24] = {15,15,7,14,14,13,13,6,12,12,11,11,5,10,10,9,9,4,8,8,3,2,1,0};
__device__ __constant__ unsigned char ctab[24] = {0,1,255,0,1,0,1,255,0,1,0,1,255,0,1,0,1,255,0,1,255,255,255,255};

// ---------------- fp32 -> bf16 conversion ----------------
__global__ void cvt_kernel(const float* __restrict__ in, unsigned short* __restrict__ out, int n) {
    int i = (blockIdx.x * blockDim.x + threadIdx.x) * 4;
    if (i >= n) return;
    f32x4 v = *(const f32x4*)(in + i);
    ushort4v o;
    o[0] = f32_to_bf16(v[0]); o[1] = f32_to_bf16(v[1]);
    o[2] = f32_to_bf16(v[2]); o[3] = f32_to_bf16(v[3]);
    *(ushort4v*)(out + i) = o;
}

// ---------------- fp32 -> bf16 transpose: out[c][r] = bf16(in[r][c]) ----------------
__global__ __launch_bounds__(256) void tcvt_kernel(const float* __restrict__ in,
                                                   unsigned short* __restrict__ out,
                                                   int R, int Cn) {
    __shared__ float tl[32][33];
    const int tx = threadIdx.x & 31, ty = threadIdx.x >> 5;
    const int c0 = blockIdx.x * 32, r0 = blockIdx.y * 32;
#pragma unroll
    for (int rr = 0; rr < 4; ++rr) {
        int r = ty + rr * 8;
        tl[r][tx] = in[(size_t)(r0 + r) * Cn + c0 + tx];
    }
    __syncthreads();
#pragma unroll
    for (int rr = 0; rr < 4; ++rr) {
        int cc = ty + rr * 8;
        out[(size_t)(c0 + cc) * R + r0 + tx] = f32_to_bf16(tl[tx][cc]);
    }
}

// ---------------- bf16 MFMA GEMM, 2-phase double-buffered: C = A @ Bt^T ----------------
template<bool OUT_BF16, bool SCALE_Q>
__global__ __launch_bounds__(256) void gemm_kernel(
    const unsigned short* __restrict__ A,
    const unsigned short* __restrict__ Bt,
    void* __restrict__ C, int K, int ldc)
{
    __shared__ __align__(16) unsigned short As[2][4096];
    __shared__ __align__(16) unsigned short Bs[2][4096];

    const int tid = threadIdx.x;
    const int lane = tid & 63;
    const int w = tid >> 6;
    const int wr = w >> 1, wc = w & 1;
    const int g = lane >> 4, ci = lane & 15;
    const int bx = blockIdx.x, by = blockIdx.y;
    const int soff = w * 1024 + lane * 16;       // staging byte offset (i=0)
    const int srow = soff >> 6;                  // 64B (BK=32 bf16) per row
    const int scch = (soff >> 4) & 3;

#define GSTAGE(buf, k0_) do { \
    _Pragma("unroll") for (int i_ = 0; i_ < 2; ++i_) { \
        int row_ = srow + i_ * 64; \
        gload_lds16(A  + (size_t)(by * 128 + row_) * K + (k0_) + scch * 8, \
                    (char*)As[buf] + i_ * 4096 + w * 1024); \
        gload_lds16(Bt + (size_t)(bx * 128 + row_) * K + (k0_) + scch * 8, \
                    (char*)Bs[buf] + i_ * 4096 + w * 1024); } } while (0)

    f32x4 acc[4][4];
#pragma unroll
    for (int i = 0; i < 4; ++i)
#pragma unroll
        for (int j = 0; j < 4; ++j) acc[i][j] = f32x4{0.f, 0.f, 0.f, 0.f};

    GSTAGE(0, 0);
    asm volatile("s_waitcnt vmcnt(0)" ::: "memory");
    __builtin_amdgcn_sched_barrier(0);
    __builtin_amdgcn_s_barrier();
    __builtin_amdgcn_sched_barrier(0);

    const int nk = K >> 5;
    for (int kt = 0; kt < nk; ++kt) {
        const int cur = kt & 1;
        if (kt + 1 < nk) GSTAGE(cur ^ 1, (kt + 1) << 5);   // issue next stage first

        bf16x8 af[4], bfr[4];
#pragma unroll
        for (int mf = 0; mf < 4; ++mf) af[mf]  = load_bf16x8(&As[cur][(wr * 64 + mf * 16 + ci) * 32 + g * 8]);
#pragma unroll
        for (int nf = 0; nf < 4; ++nf) bfr[nf] = load_bf16x8(&Bs[cur][(wc * 64 + nf * 16 + ci) * 32 + g * 8]);
#pragma unroll
        for (int mf = 0; mf < 4; ++mf)
#pragma unroll
            for (int nf = 0; nf < 4; ++nf)
                acc[mf][nf] = __builtin_amdgcn_mfma_f32_16x16x32_bf16(af[mf], bfr[nf], acc[mf][nf], 0, 0, 0);

        asm volatile("s_waitcnt vmcnt(0) lgkmcnt(0)" ::: "memory");
        __builtin_amdgcn_sched_barrier(0);
        __builtin_amdgcn_s_barrier();
        __builtin_amdgcn_sched_barrier(0);
    }
#undef GSTAGE

#pragma unroll
    for (int mf = 0; mf < 4; ++mf)
#pragma unroll
        for (int nf = 0; nf < 4; ++nf)
#pragma unroll
            for (int r = 0; r < 4; ++r) {
                int row = by * 128 + wr * 64 + mf * 16 + g * 4 + r;
                int col = bx * 128 + wc * 64 + nf * 16 + ci;
                float v = acc[mf][nf][r];
                if (SCALE_Q && col < 1024) v *= 0.1803368801f;  // D^-0.5 * log2(e)
                if (OUT_BF16)
                    ((unsigned short*)C)[(size_t)row * ldc + col] = f32_to_bf16(v);
                else
                    ((float*)C)[(size_t)row * ldc + col] = v;
            }
}

// ---------------- causal flash attention, kv-split chunks, depth-2 pipeline ----------------
// 768 blocks: full q-tiles (qb 0..7) write attn directly; q-tiles 8..15 are split into two
// kv chunks writing unnormalized partial (O bf16, m/l fp32) for the combine kernel.
__global__ __launch_bounds__(256) void attn5_kernel(const unsigned short* __restrict__ qkv,
                                                    unsigned short* __restrict__ attn,
                                                    unsigned short* __restrict__ Obuf,
                                                    float* __restrict__ mlbuf) {
    constexpr int T = 2048, HD3 = 3072, Cc = 1024;
    __shared__ __align__(16) unsigned short Ks[3][4096];  // [64 kv][64 d], col ^= (row&7)*8
    __shared__ __align__(16) unsigned short Vt[2][4096];  // [64 d][64 kv], col ^= ((d^(d>>3))&7)*8

    const int tid = threadIdx.x;
    const int lane = tid & 63;
    const int w = tid >> 6;
    const int l31 = lane & 31;
    const int hi = lane >> 5;

    const int bx = blockIdx.x;
    const int j = bx >> 5;            // 0..23 (LPT-ordered work item)
    const int bh = bx & 31;
    const int q = qtab[j];
    const int ct = ctab[j];           // 255 = full, 0/1 = kv chunk
    const int h = bh & 15;
    const int b = bh >> 4;
    const int q0w = q * 128 + w * 32;
    const int qrow = q0w + l31;
    const size_t base = (size_t)b * T * HD3;

    const int nt_full = 2 * q + 2;
    const int ts = (ct == 1) ? (q + 1) : 0;
    const int te = (ct == 0) ? (q + 1) : nt_full;
    const int ntc = te - ts;          // >= 2 always (chunks only for q>=8)

    bf16x8 qf[4];   // B-operand: lane holds Q[qrow][t*16 + hi*8 + j] (q pre-scaled in GEMM1)
#pragma unroll
    for (int t = 0; t < 4; ++t)
        qf[t] = load_bf16x8(qkv + base + (size_t)qrow * HD3 + h * 64 + t * 16 + hi * 8);

    f32x16 acc0 = vzero16(), acc1 = vzero16();  // O^T: col=q(lane), row d = rr+8G+4hi (+32)
    float m = -3e38f, l = 0.f;

    ushort8 vA0, vA1, vB0, vB1;
#define LOADV(tile, r0, r1) do { int kv0_ = (tile) * 64; \
    int rr0_ = tid >> 3, cc0_ = tid & 7; \
    r0 = *(const ushort8*)(qkv + base + (size_t)(kv0_ + rr0_) * HD3 + 2 * Cc + h * 64 + cc0_ * 8); \
    int c1_ = 256 + tid; int rr1_ = c1_ >> 3, cc1_ = c1_ & 7; \
    r1 = *(const ushort8*)(qkv + base + (size_t)(kv0_ + rr1_) * HD3 + 2 * Cc + h * 64 + cc1_ * 8); } while (0)

#define DMAK(tile, kb) do { int kv0_ = (tile) * 64; \
    _Pragma("unroll") for (int i_ = 0; i_ < 2; ++i_) { \
        int off_ = i_ * 4096 + w * 1024 + lane * 16; \
        int row_ = off_ >> 7; \
        int csw_ = ((lane & 7) * 8) ^ ((row_ & 7) * 8); \
        gload_lds16(qkv + base + (size_t)(kv0_ + row_) * HD3 + Cc + h * 64 + csw_, \
                    (void*)(((char*)&Ks[kb][0]) + i_ * 4096 + w * 1024)); } } while (0)

#define WRITEV(vb, r0, r1) do { \
    _Pragma("unroll") for (int i_ = 0; i_ < 2; ++i_) { \
        int c_ = i_ * 256 + tid; int row_ = c_ >> 3, cc_ = c_ & 7; \
        ushort8 v_ = i_ ? r1 : r0; \
        _Pragma("unroll") for (int j_ = 0; j_ < 8; ++j_) { \
            int d_ = cc_ * 8 + j_; \
            int sw_ = ((d_ ^ (d_ >> 3)) & 7) * 8; \
            Vt[vb][d_ * 64 + (row_ ^ sw_)] = v_[j_]; } } } while (0)

    // prologue: tile ts fully staged; tile ts+1 in flight
    LOADV(ts, vA0, vA1);
    DMAK(ts, 0);
    asm volatile("s_waitcnt vmcnt(0)" ::: "memory");
    __builtin_amdgcn_sched_barrier(0);
    WRITEV(0, vA0, vA1);
    LOADV(ts + 1, vB0, vB1);
    DMAK(ts + 1, 1);
    asm volatile("s_waitcnt lgkmcnt(0)" ::: "memory");
    __builtin_amdgcn_sched_barrier(0);
    __builtin_amdgcn_s_barrier();
    __builtin_amdgcn_sched_barrier(0);

    for (int tt = 0; tt < ntc; ++tt) {
        const int t = ts + tt;
        const int kv0 = t * 64;
        const int kcur = tt % 3;
        const int vcur = tt & 1;
        const bool act = (kv0 <= q0w + 31);
        const bool pre2 = (tt + 2) < ntc;

        // 1. write V(t+1) to LDS (regs 1 tile old -> implicit vmem wait here is free)
        if (tt + 1 < ntc) {
            if (tt & 1) WRITEV(vcur ^ 1, vA0, vA1); else WRITEV(vcur ^ 1, vB0, vB1);
        }
        // 2. issue prefetch for tile t+2 (V->regs, K->LDS buf (tt+2)%3)
        if (pre2) {
            if (tt & 1) LOADV(t + 2, vB0, vB1); else LOADV(t + 2, vA0, vA1);
            DMAK(t + 2, (tt + 2) % 3);
        }

        if (act) {
            f32x16 s0 = vzero16(), s1 = vzero16();
            bf16x8 pf[4];
            const bool st1_ok = (kv0 + 32 <= q0w + 31);
            __builtin_amdgcn_s_setprio(1);
#pragma unroll
            for (int tf = 0; tf < 4; ++tf) {  // st = 0
                int row = l31;
                int idx = kcur * 4096 + row * 64 + ((tf * 16 + hi * 8) ^ ((row & 7) * 8));
                s0 = __builtin_amdgcn_mfma_f32_32x32x16_bf16(load_bf16x8(&Ks[0][idx]), qf[tf], s0, 0, 0, 0);
            }
            if (st1_ok) {
#pragma unroll
                for (int tf = 0; tf < 4; ++tf) {  // st = 1
                    int row = 32 + l31;
                    int idx = kcur * 4096 + row * 64 + ((tf * 16 + hi * 8) ^ ((row & 7) * 8));
                    s1 = __builtin_amdgcn_mfma_f32_32x32x16_bf16(load_bf16x8(&Ks[0][idx]), qf[tf], s1, 0, 0, 0);
                }
            }
            __builtin_amdgcn_s_setprio(0);
            const bool needmask = (kv0 + 63 > q0w);
            if (needmask) {
#pragma unroll
                for (int G = 0; G < 4; ++G)
#pragma unroll
                    for (int rr = 0; rr < 4; ++rr) {
                        int kvb = kv0 + 8 * G + 4 * hi + rr;  // kv of C-reg (crow formula, HW-verified)
                        s0[G * 4 + rr] = (kvb      <= qrow) ? s0[G * 4 + rr] : -3e38f;
                        s1[G * 4 + rr] = (kvb + 32 <= qrow) ? s1[G * 4 + rr] : -3e38f;
                    }
            }
            float pmax = tmax32(s0, s1);
            pmax = fmaxf(pmax, __shfl_xor(pmax, 32));   // HW-verified exchange
            // defer-max (T13): skip O/l rescale while pmax - m <= 11.5 (log2 domain)
            if (!__all(pmax - m <= 11.5f)) {
                float mnew = fmaxf(m, pmax);
                float alpha = exp2f(m - mnew);
                m = mnew;
                l *= alpha;
#pragma unroll
                for (int i = 0; i < 16; ++i) { acc0[i] *= alpha; acc1[i] *= alpha; }
            }
#pragma unroll
            for (int i = 0; i < 16; ++i) {
                s0[i] = exp2f(s0[i] - m);
                s1[i] = exp2f(s1[i] - m);
            }

            // P -> B-fragments (cvt_pk + lane<->lane+32 exchange, HW-verified construction)
            unsigned pk0[4][2], pk1[4][2];
#pragma unroll
            for (int G = 0; G < 4; ++G) {
                pk0[G][0] = cvt_pk_bf16(s0[G * 4 + 0], s0[G * 4 + 1]);
                pk0[G][1] = cvt_pk_bf16(s0[G * 4 + 2], s0[G * 4 + 3]);
                pk1[G][0] = cvt_pk_bf16(s1[G * 4 + 0], s1[G * 4 + 1]);
                pk1[G][1] = cvt_pk_bf16(s1[G * 4 + 2], s1[G * 4 + 3]);
            }
#pragma unroll
            for (int tf = 0; tf < 4; ++tf) {
                const int kb = tf & 1;
                unsigned sA0, sA1, sB0, sB1;
                if (tf < 2) { sA0 = pk0[2 * kb][0]; sA1 = pk0[2 * kb][1]; sB0 = pk0[2 * kb + 1][0]; sB1 = pk0[2 * kb + 1][1]; }
                else        { sA0 = pk1[2 * kb][0]; sA1 = pk1[2 * kb][1]; sB0 = pk1[2 * kb + 1][0]; sB1 = pk1[2 * kb + 1][1]; }
                unsigned sd0 = hi ? sA0 : sB0, sd1 = hi ? sA1 : sB1;
                unsigned rc0 = (unsigned)__shfl_xor((int)sd0, 32);
                unsigned rc1 = (unsigned)__shfl_xor((int)sd1, 32);
                uint4v u;
                u[0] = hi ? rc0 : sA0;  u[1] = hi ? rc1 : sA1;   // k = hi*8 + 0..3
                u[2] = hi ? sB0 : rc0;  u[3] = hi ? sB1 : rc1;   // k = hi*8 + 4..7
                pf[tf] = __builtin_bit_cast(bf16x8, u);
            }

            __builtin_amdgcn_s_setprio(1);
#pragma unroll
            for (int tf = 0; tf < 4; ++tf) {
                {
                    int d = l31, sw = ((d ^ (d >> 3)) & 7) * 8;
                    bf16x8 vf = load_bf16x8(&Vt[vcur][d * 64 + ((tf * 16 + hi * 8) ^ sw)]);
                    acc0 = __builtin_amdgcn_mfma_f32_32x32x16_bf16(vf, pf[tf], acc0, 0, 0, 0);
                }
                {
                    int d = 32 + l31, sw = ((d ^ (d >> 3)) & 7) * 8;
                    bf16x8 vf = load_bf16x8(&Vt[vcur][d * 64 + ((tf * 16 + hi * 8) ^ sw)]);
                    acc1 = __builtin_amdgcn_mfma_f32_32x32x16_bf16(vf, pf[tf], acc1, 0, 0, 0);
                }
            }
            __builtin_amdgcn_s_setprio(0);

            // row-sum + l update off the PV critical path
            float rsum = tsum32(s0, s1);
            l += rsum + __shfl_xor(rsum, 32);
        }

        // counted-vmcnt barrier: guarantee K(t+1) landed, keep t+2 prefetch in flight
        if (pre2) asm volatile("s_waitcnt vmcnt(4) lgkmcnt(0)" ::: "memory");
        else      asm volatile("s_waitcnt vmcnt(0) lgkmcnt(0)" ::: "memory");
        __builtin_amdgcn_sched_barrier(0);
        __builtin_amdgcn_s_barrier();
        __builtin_amdgcn_sched_barrier(0);
    }

    if (ct == 255) {
        // full q-tile: normalize and write attn
        const float invl = 1.0f / l;
        const size_t ob = (size_t)b * T * Cc + (size_t)qrow * Cc + h * 64;
#pragma unroll
        for (int G = 0; G < 4; ++G) {
            ushort4v o0, o1;
#pragma unroll
            for (int rr = 0; rr < 4; ++rr) {
                o0[rr] = f32_to_bf16(acc0[G * 4 + rr] * invl);
                o1[rr] = f32_to_bf16(acc1[G * 4 + rr] * invl);
            }
            int d0 = 8 * G + 4 * hi;
            *(ushort4v*)(attn + ob + d0) = o0;
            *(ushort4v*)(attn + ob + 32 + d0) = o1;
        }
    } else {
        // chunk: write unnormalized partial O (bf16) + m,l (fp32)
        const int slot = bh * 16 + (q - 8) * 2 + ct;
        const int qlocal = w * 32 + l31;
        unsigned short* op = Obuf + (size_t)slot * 8192 + qlocal * 64;
#pragma unroll
        for (int G = 0; G < 4; ++G) {
            ushort4v o0, o1;
#pragma unroll
            for (int rr = 0; rr < 4; ++rr) {
                o0[rr] = f32_to_bf16(acc0[G * 4 + rr]);
                o1[rr] = f32_to_bf16(acc1[G * 4 + rr]);
            }
            int d0 = 8 * G + 4 * hi;
            *(ushort4v*)(op + d0) = o0;
            *(ushort4v*)(op + 32 + d0) = o1;
        }
        if (hi == 0) {
            mlbuf[slot * 256 + qlocal * 2]     = m;
            mlbuf[slot * 256 + qlocal * 2 + 1] = l;
        }
    }
#undef LOADV
#undef DMAK
#undef WRITEV
}

// ---------------- combine: merge the two kv-chunks of each split q-tile ----------------
__global__ __launch_bounds__(256) void combine_kernel(const unsigned short* __restrict__ Obuf,
                                                      const float* __restrict__ mlbuf,
                                                      unsigned short* __restrict__ attn) {
    constexpr int T = 2048, Cc = 1024;
    const int ss = blockIdx.x;            // 0..255: (bh, qq)
    const int bh = ss >> 3, qq = 8 + (ss & 7);
    const int b = bh >> 4, h = bh & 15;
    const int slot0 = bh * 16 + (qq - 8) * 2;
    const int tid = threadIdx.x;
    const int qlocal = tid >> 1, dh = (tid & 1) * 32;

    const float* ml0 = mlbuf + (size_t)slot0 * 256 + qlocal * 2;
    const float* ml1 = ml0 + 256;
    float m0 = ml0[0], l0 = ml0[1], m1 = ml1[0], l1 = ml1[1];
    float M = fmaxf(m0, m1);
    float w0 = exp2f(m0 - M), w1 = exp2f(m1 - M);
    float inv = 1.f / (w0 * l0 + w1 * l1);

    const unsigned short* p0 = Obuf + (size_t)slot0 * 8192 + qlocal * 64 + dh;
    const unsigned short* p1 = p0 + 8192;
    unsigned short* po = attn + (size_t)b * T * Cc + (size_t)(qq * 128 + qlocal) * Cc + h * 64 + dh;
#pragma unroll
    for (int i = 0; i < 4; ++i) {
        ushort8 a = *(const ushort8*)(p0 + i * 8);
        ushort8 c = *(const ushort8*)(p1 + i * 8);
        ushort8 o;
#pragma unroll
        for (int k = 0; k < 8; ++k)
            o[k] = f32_to_bf16((w0 * bf16_to_f32(a[k]) + w1 * bf16_to_f32(c[k])) * inv);
        *(ushort8*)(po + i * 8) = o;
    }
}

extern "C" void kernel_launch(void* const* d_in, const int* in_sizes, int n_in,
                              void* d_out, int out_size, void* d_ws, size_t ws_size,
                              hipStream_t stream) {
    const float* x     = (const float*)d_in[0];
    // d_in[1] = mask (tril -> causal predicate), unused
    const float* w_qkv = (const float*)d_in[2];
    const float* w_out = (const float*)d_in[3];
    // d_in[4] = charge_w: provably no-op, unused
    float* out = (float*)d_out;

    // workspace (bf16 elements)
    unsigned short* xb     = (unsigned short*)d_ws;
    unsigned short* wqkvT  = xb + 4194304;        // [3072][1024]
    unsigned short* woutT  = wqkvT + 3145728;     // [1024][1024]
    unsigned short* qkv    = woutT + 1048576;     // [4096][3072]
    unsigned short* attn   = qkv + 12582912;      // [4096][1024]
    // partials alias regions that are dead after GEMM1:
    unsigned short* Obuf   = xb;                  // 512 slots x 128 x 64 bf16 = 8 MB
    float*          mlbuf  = (float*)wqkvT;       // 512 slots x 128 x 2 fp32 = 512 KB

    cvt_kernel<<<4096, 256, 0, stream>>>(x, xb, 4194304);
    tcvt_kernel<<<dim3(96, 32), 256, 0, stream>>>(w_qkv, wqkvT, 1024, 3072);
    tcvt_kernel<<<dim3(32, 32), 256, 0, stream>>>(w_out, woutT, 1024, 1024);

    // qkv = xb @ w_qkv (M=4096, N=3072, K=1024), bf16 out, q-columns pre-scaled
    gemm_kernel<true, true><<<dim3(24, 32), 256, 0, stream>>>(xb, wqkvT, (void*)qkv, 1024, 3072);

    // causal attention: 768 LPT-ordered blocks (full tiles + kv-split chunks)
    attn5_kernel<<<768, 256, 0, stream>>>(qkv, attn, Obuf, mlbuf);
    combine_kernel<<<256, 256, 0, stream>>>(Obuf, mlbuf, attn);

    // out = attn @ w_out (M=4096, N=1024, K=1024), fp32 out
    gemm_kernel<false, false><<<dim3(8, 32), 256, 0, stream>>>(attn, woutT, (void*)out, 1024, 1024);
}